// Round 1
// baseline (221.301 us; speedup 1.0000x reference)
//
#include <hip/hip_runtime.h>
#include <math.h>

// AGREE group-recommendation forward, fp32 scalar, 1 thread = 1 batch element.
// Compute-bound: ~3K FMA/elem, no fp32 MFMA on CDNA4 -> vector ALU floor ~40us.
// Weights are read with wave-uniform compile-time-indexed addresses so the
// compiler emits s_load -> SGPR broadcast (no LDS, no VMEM for weights).

#define DD 32

__global__ __launch_bounds__(256) void agree_fwd(
    const int* __restrict__ gi, const int* __restrict__ ii,
    const int* __restrict__ gm,
    const float* __restrict__ ue, const float* __restrict__ itemb,
    const float* __restrict__ w1, const float* __restrict__ b1,
    const float* __restrict__ w2, const float* __restrict__ b2,
    const float* __restrict__ pw1, const float* __restrict__ pb1,
    const float* __restrict__ pw2, const float* __restrict__ pb2,
    float* __restrict__ out, int B)
{
    int b = blockIdx.x * blockDim.x + threadIdx.x;
    if (b >= B) return;

    int g  = gi[b];
    int it = ii[b];
    int m0 = gm[3 * g + 0];
    int m1 = gm[3 * g + 1];
    int m2 = gm[3 * g + 2];

    // ---- gather embeddings (float4, 16B aligned: rows are 128B) ----
    float me[3][DD];   // member embeddings
    float iev[DD];     // item embedding
    {
        const float4* p0 = reinterpret_cast<const float4*>(ue + (size_t)m0 * DD);
        const float4* p1 = reinterpret_cast<const float4*>(ue + (size_t)m1 * DD);
        const float4* p2 = reinterpret_cast<const float4*>(ue + (size_t)m2 * DD);
        const float4* p3 = reinterpret_cast<const float4*>(itemb + (size_t)it * DD);
        #pragma unroll
        for (int q = 0; q < DD / 4; ++q) {
            float4 v0 = p0[q];
            float4 v1 = p1[q];
            float4 v2 = p2[q];
            float4 v3 = p3[q];
            me[0][4*q+0] = v0.x; me[0][4*q+1] = v0.y; me[0][4*q+2] = v0.z; me[0][4*q+3] = v0.w;
            me[1][4*q+0] = v1.x; me[1][4*q+1] = v1.y; me[1][4*q+2] = v1.z; me[1][4*q+3] = v1.w;
            me[2][4*q+0] = v2.x; me[2][4*q+1] = v2.y; me[2][4*q+2] = v2.z; me[2][4*q+3] = v2.w;
            iev[4*q+0]   = v3.x; iev[4*q+1]   = v3.y; iev[4*q+2]   = v3.z; iev[4*q+3]   = v3.w;
        }
    }

    // ---- attention layer 1: h = relu(x @ w1 + b1), x = [me0,me1,me2,ie] (128) ----
    float h[16];
    #pragma unroll
    for (int j = 0; j < 16; ++j) h[j] = b1[j];

    #pragma unroll
    for (int m = 0; m < 3; ++m) {
        #pragma unroll
        for (int k = 0; k < DD; ++k) {
            float xk = me[m][k];
            #pragma unroll
            for (int j = 0; j < 16; ++j)
                h[j] = fmaf(xk, w1[(m * DD + k) * 16 + j], h[j]);
        }
    }
    #pragma unroll
    for (int k = 0; k < DD; ++k) {
        float xk = iev[k];
        #pragma unroll
        for (int j = 0; j < 16; ++j)
            h[j] = fmaf(xk, w1[(3 * DD + k) * 16 + j], h[j]);
    }
    #pragma unroll
    for (int j = 0; j < 16; ++j) h[j] = fmaxf(h[j], 0.0f);

    // ---- attention layer 2 + softmax over 3 members ----
    float l0 = b2[0], l1 = b2[1], l2 = b2[2];
    #pragma unroll
    for (int j = 0; j < 16; ++j) {
        l0 = fmaf(h[j], w2[j * 3 + 0], l0);
        l1 = fmaf(h[j], w2[j * 3 + 1], l1);
        l2 = fmaf(h[j], w2[j * 3 + 2], l2);
    }
    float mx = fmaxf(l0, fmaxf(l1, l2));
    float e0 = __expf(l0 - mx);
    float e1 = __expf(l1 - mx);
    float e2 = __expf(l2 - mx);
    float inv = 1.0f / (e0 + e1 + e2);
    float wt0 = e0 * inv, wt1 = e1 * inv, wt2 = e2 * inv;

    // ---- fused: g = sum_m wt[m]*me[m]; new=[g*ie, g, ie]; h2 = relu(new@pw1+pb1) ----
    float h2[8];
    #pragma unroll
    for (int j = 0; j < 8; ++j) h2[j] = pb1[j];

    #pragma unroll
    for (int d = 0; d < DD; ++d) {
        float gd  = wt0 * me[0][d] + wt1 * me[1][d] + wt2 * me[2][d];
        float gie = gd * iev[d];
        #pragma unroll
        for (int j = 0; j < 8; ++j) {
            h2[j] = fmaf(gie,    pw1[d * 8 + j],            h2[j]);
            h2[j] = fmaf(gd,     pw1[(DD + d) * 8 + j],     h2[j]);
            h2[j] = fmaf(iev[d], pw1[(2 * DD + d) * 8 + j], h2[j]);
        }
    }

    // ---- prediction layer 2 + sigmoid ----
    float z = pb2[0];
    #pragma unroll
    for (int j = 0; j < 8; ++j)
        z = fmaf(fmaxf(h2[j], 0.0f), pw2[j], z);

    out[b] = 1.0f / (1.0f + __expf(-z));
}

extern "C" void kernel_launch(void* const* d_in, const int* in_sizes, int n_in,
                              void* d_out, int out_size, void* d_ws, size_t ws_size,
                              hipStream_t stream) {
    int B = in_sizes[0];
    dim3 block(256);
    dim3 grid((B + 255) / 256);
    hipLaunchKernelGGL(agree_fwd, grid, block, 0, stream,
        (const int*)d_in[0],    // group_inputs
        (const int*)d_in[1],    // item_inputs
        (const int*)d_in[2],    // group_members
        (const float*)d_in[3],  // user_emb
        (const float*)d_in[4],  // item_emb
        (const float*)d_in[5],  // att_w1
        (const float*)d_in[6],  // att_b1
        (const float*)d_in[7],  // att_w2
        (const float*)d_in[8],  // att_b2
        (const float*)d_in[9],  // pred_w1
        (const float*)d_in[10], // pred_b1
        (const float*)d_in[11], // pred_w2
        (const float*)d_in[12], // pred_b2
        (float*)d_out, B);
}